// Round 2
// 382.405 us; speedup vs baseline: 1.0270x; 1.0270x over previous
//
#include <hip/hip_runtime.h>

// Problem constants
#define DIMC 192
#define HID  48          // DIM / RED
#define HW   65536       // 256*256
#define WIDTH 256
#define NPLANE 768       // B * DIM

// Native Clang vector type — required by __builtin_nontemporal_store
// (HIP's float4 is a class and is rejected). Same 16B layout.
typedef float nfloat4 __attribute__((ext_vector_type(4)));

// ---------------------------------------------------------------------------
// Kernel 1: per-(b,c) mean over the 256x256 plane.
// 768 blocks x 1024 threads; each thread sums 16 float4 (64 floats), then
// wave shuffle-reduce + LDS cross-wave reduce.
// Normal (caching) loads ON PURPOSE: this pass warms the 256 MiB Infinity
// Cache with x (192 MiB) so the conv pass re-reads it from L3, not HBM.
// ---------------------------------------------------------------------------
__global__ __launch_bounds__(1024) void k_pool(const float* __restrict__ x,
                                               float* __restrict__ pooled) {
    const int plane = blockIdx.x;  // 0..767
    const float4* p = (const float4*)(x + (size_t)plane * HW);
    const int t = threadIdx.x;
    float s = 0.f;
#pragma unroll
    for (int k = 0; k < 16; ++k) {
        float4 v = p[k * 1024 + t];
        s += (v.x + v.y) + (v.z + v.w);
    }
    // wave (64-lane) reduce
#pragma unroll
    for (int off = 32; off > 0; off >>= 1) s += __shfl_down(s, off, 64);
    __shared__ float wsum[16];
    const int wave = t >> 6, lane = t & 63;
    if (lane == 0) wsum[wave] = s;
    __syncthreads();
    if (t == 0) {
        float tot = 0.f;
#pragma unroll
        for (int i = 0; i < 16; ++i) tot += wsum[i];
        pooled[plane] = tot * (1.0f / 65536.0f);
    }
}

// ---------------------------------------------------------------------------
// Kernel 2 (fused): weight generation prologue + 4-tap masked depthwise conv.
//
// Prologue (per block, redundant across the 8 row-tiles x 192 channels — 58M
// FMA total, VALU noise): t = relu(BN(pooled[b] @ w1^T)) via 48 groups of 4
// lanes; then 4 taps for THIS channel c from w2 rows c*9+{0,1,2,3}.
// This deletes the old 4-block k_weights dispatch and its full-GPU drain.
//
// Conv: out[y][x] = w00*X[y-1][x-1] + w01*X[y-1][x] + w02*X[y-1][x+1]
//                 + w10*X[y  ][x-1] + bias[c]
// One wave per group of 8 consecutive rows; 64 lanes x float4 cover one
// 256-px row. Column halos via wave shuffles; row halo is the rolling
// register from the previous iteration.
// Stores are NON-TEMPORAL: output is write-once, never re-read. Keeping it
// out of L2/L3 preserves x's L3 residency (set up by k_pool) so our x reads
// are Infinity-Cache hits instead of a second HBM stream.
// Grid: 768 planes * 8 row-tiles = 6144 blocks; block = 4 waves (8 rows each).
// ---------------------------------------------------------------------------
__global__ __launch_bounds__(256) void k_conv(
    const float* __restrict__ x,
    const float* __restrict__ pooled,   // [4,192]
    const float* __restrict__ w1,       // [48,192]
    const float* __restrict__ gamma,
    const float* __restrict__ beta,
    const float* __restrict__ rmean,
    const float* __restrict__ rvar,
    const float* __restrict__ w2,       // [1728,48]
    const float* __restrict__ b2,       // [1728]
    const float* __restrict__ bias,
    float* __restrict__ out)
{
    const int plane = blockIdx.x >> 3;          // 0..767 (= b*192 + c)
    const int b = plane / DIMC;
    const int c = plane - b * DIMC;
    const int tid = threadIdx.x;

    // ---- weight-gen prologue ----
    __shared__ float T[HID];
    __shared__ float W4[4];
    {
        // 48 groups of 4 lanes compute t[g] (waves 0..2 active, wave 3 skips)
        const int g = tid >> 2, l = tid & 3;
        if (g < HID) {
            const float* pr = pooled + b * DIMC;
            const float* wr = w1 + g * DIMC;
            float acc = 0.f;
#pragma unroll 8
            for (int d = l; d < DIMC; d += 4) acc += pr[d] * wr[d];
            acc += __shfl_xor(acc, 1, 64);
            acc += __shfl_xor(acc, 2, 64);
            if (l == 0) {
                const float inv = rsqrtf(rvar[g] + 1e-5f);
                float v = gamma[g] * (acc - rmean[g]) * inv + beta[g];
                T[g] = v > 0.f ? v : 0.f;
            }
        }
        __syncthreads();
        // 4 taps for this channel: rows c*9+0..3 of w2 (taps 4..8 are masked)
        if (tid < 4) {
            const int o = c * 9 + tid;
            const float* wr = w2 + o * HID;
            float acc = b2[o];
#pragma unroll
            for (int j = 0; j < HID; ++j) acc += T[j] * wr[j];
            W4[tid] = acc;
        }
        __syncthreads();
    }
    const float4 wt = make_float4(W4[0], W4[1], W4[2], W4[3]); // {w00,w01,w02,w10}
    const float bs = bias[c];

    // ---- conv ----
    const int wave = tid >> 6;
    const int lane = tid & 63;
    const int y0 = ((blockIdx.x & 7) << 5) + (wave << 3);
    const float4* xp = (const float4*)(x + (size_t)plane * HW);
    nfloat4* op = (nfloat4*)(out + (size_t)plane * HW);

    float4 a;                                   // row y-1
    if (y0 == 0) a = make_float4(0.f, 0.f, 0.f, 0.f);
    else         a = xp[(y0 - 1) * 64 + lane];

#pragma unroll
    for (int r = 0; r < 8; ++r) {
        const int y = y0 + r;
        float4 bb = xp[y * 64 + lane];          // row y
        float leftA  = __shfl_up(a.w, 1, 64);   if (lane == 0)  leftA  = 0.f;
        float rightA = __shfl_down(a.x, 1, 64); if (lane == 63) rightA = 0.f;
        float leftB  = __shfl_up(bb.w, 1, 64);  if (lane == 0)  leftB  = 0.f;
        nfloat4 o;
        o.x = wt.x * leftA + wt.y * a.x + wt.z * a.y    + wt.w * leftB + bs;
        o.y = wt.x * a.x   + wt.y * a.y + wt.z * a.z    + wt.w * bb.x  + bs;
        o.z = wt.x * a.y   + wt.y * a.z + wt.z * a.w    + wt.w * bb.y  + bs;
        o.w = wt.x * a.z   + wt.y * a.w + wt.z * rightA + wt.w * bb.z  + bs;
        __builtin_nontemporal_store(o, &op[y * 64 + lane]);  // don't pollute L2/L3
        a = bb;                                 // roll: row y becomes row y-1
    }
}

// ---------------------------------------------------------------------------
extern "C" void kernel_launch(void* const* d_in, const int* in_sizes, int n_in,
                              void* d_out, int out_size, void* d_ws, size_t ws_size,
                              hipStream_t stream) {
    const float* x     = (const float*)d_in[0];
    const float* w1    = (const float*)d_in[1];
    const float* gamma = (const float*)d_in[2];
    const float* beta  = (const float*)d_in[3];
    const float* rmean = (const float*)d_in[4];
    const float* rvar  = (const float*)d_in[5];
    const float* w2    = (const float*)d_in[6];
    const float* b2    = (const float*)d_in[7];
    const float* bias  = (const float*)d_in[8];
    float* out = (float*)d_out;

    float* pooled = (float*)d_ws;        // 768 floats

    k_pool<<<NPLANE, 1024, 0, stream>>>(x, pooled);
    k_conv<<<NPLANE * 8, 256, 0, stream>>>(x, pooled, w1, gamma, beta,
                                           rmean, rvar, w2, b2, bias, out);
}